// Round 1
// baseline (69.913 us; speedup 1.0000x reference)
//
#include <hip/hip_runtime.h>
#include <stdint.h>

#define M_BOXES 8192
#define MIN_CONF_F 0.25f
#define MIN_IOU_F 0.45f
#define VCAP 4096
#define NT 1024

typedef unsigned long long u64;

__device__ inline float scalar_to_float(const int* p) {
    int v = p[0];
    if (v > 0 && v < (1 << 20)) return (float)v;   // plain int (int32 or low word of int64)
    return __int_as_float(v);                      // was actually float bits
}

__device__ inline u64 shfl_u64(u64 v, int src) {
    int lo = __shfl((int)(v & 0xFFFFFFFFull), src, 64);
    int hi = __shfl((int)(v >> 32), src, 64);
    return ((u64)(unsigned)hi << 32) | (unsigned)lo;
}

// Kernel 1: gather + validity compaction. Writes boxes/conf/class to d_out
// (unscaled), zeros keep region, appends packed keys for valid entries.
__global__ __launch_bounds__(256) void gather_kernel(
    const float* __restrict__ boxes_raw, const float* __restrict__ scores,
    const int* __restrict__ indices, const int* __restrict__ p_out_h,
    const int* __restrict__ p_out_w, float* __restrict__ out,
    u64* __restrict__ vpack, int* __restrict__ vcount)
{
    int i = blockIdx.x * blockDim.x + threadIdx.x;
    if (i >= M_BOXES) return;
    int cls = indices[3 * i + 1];
    int idx = indices[3 * i + 2];
    float conf = scores[cls * M_BOXES + idx];
    float4 b = *reinterpret_cast<const float4*>(boxes_raw + 4 * idx); // y1,x1,y2,x2
    float W = scalar_to_float(p_out_w);
    float H = scalar_to_float(p_out_h);
    float x1 = fminf(fmaxf(b.y, 0.f), W);
    float y1 = fminf(fmaxf(b.x, 0.f), H);
    float x2 = fminf(fmaxf(b.w, 0.f), W);
    float y2 = fminf(fmaxf(b.z, 0.f), H);
    *reinterpret_cast<float4*>(out + 4 * i) = make_float4(x1, y1, x2, y2);
    out[4 * M_BOXES + i] = conf;        // conf (unscaled; finalize multiplies by keep)
    out[5 * M_BOXES + i] = (float)cls;  // class_ids output (keep-independent)
    out[6 * M_BOXES + i] = 0.f;         // keep init
    bool valid = (conf > MIN_CONF_F) &&
                 (cls == 2 || cls == 3 || cls == 5 || cls == 7);
    if (valid) {
        int p = atomicAdd(vcount, 1);
        if (p < VCAP)
            vpack[p] = ((u64)(~__float_as_uint(conf)) << 32) | (unsigned)i;
    }
}

// Kernel 2: single block. Bitonic-sort the valid keys (canonical total order:
// conf desc, orig asc == JAX stable argsort of -s), then greedy NMS.
__global__ __launch_bounds__(NT) void nms_kernel(
    float* __restrict__ out, const u64* __restrict__ vpack,
    const int* __restrict__ vcount)
{
    __shared__ __align__(16) unsigned char smem[49216];
    u64* skey = (u64*)smem;                       // [0, 32768): up to 4096 keys
    float4* sbox = (float4*)(smem + 8192);        // fast path (V<=512): boxes
    u64* sup = (u64*)(smem + 16384);              // fast path: 512 rows x 8 words
    u64* kwout = (u64*)(smem + 49152);            // final keep words

    int tid = threadIdx.x;
    int V = *vcount;
    if (V > VCAP) V = VCAP;
    unsigned n = 1;
    while (n < (unsigned)V) n <<= 1;
    if (n < 2) n = 2;

    for (unsigned s = tid; s < n; s += NT)
        skey[s] = (s < (unsigned)V) ? vpack[s] : ~0ull;
    __syncthreads();

    for (unsigned k = 2; k <= n; k <<= 1) {
        for (unsigned j = k >> 1; j > 0; j >>= 1) {
            for (unsigned t = tid; t < n; t += NT) {
                unsigned ixj = t ^ j;
                if (ixj > t) {
                    u64 a = skey[t], bb = skey[ixj];
                    bool up = ((t & k) == 0);
                    if ((a > bb) == up) { skey[t] = bb; skey[ixj] = a; }
                }
            }
            __syncthreads();
        }
    }
    // ascending by key == conf descending, index ascending

    if (V <= 512) {
        int nw = (V + 63) >> 6;
        for (int s = tid; s < V; s += NT) {
            unsigned orig = (unsigned)(skey[s] & 0xFFFFFFFFull);
            sbox[s] = *reinterpret_cast<const float4*>(out + 4 * orig);
        }
        __syncthreads();
        // suppression bit-matrix: sup[i][l] bit j-of-word set iff j>i and iou>thr
        for (int w = tid; w < V * nw; w += NT) {
            int i = w / nw, l = w - i * nw;
            float4 bi = sbox[i];
            float ai = fmaxf(bi.z - bi.x, 0.f) * fmaxf(bi.w - bi.y, 0.f);
            u64 bits = 0;
            int j0 = l << 6;
            int jend = (j0 + 64 < V) ? j0 + 64 : V;
            int js = (j0 > i + 1) ? j0 : i + 1;
            for (int j = js; j < jend; ++j) {
                float4 bj = sbox[j];
                float aj = fmaxf(bj.z - bj.x, 0.f) * fmaxf(bj.w - bj.y, 0.f);
                float ix1 = fmaxf(bi.x, bj.x);
                float iy1 = fmaxf(bi.y, bj.y);
                float ix2 = fminf(bi.z, bj.z);
                float iy2 = fminf(bi.w, bj.w);
                float inter = fmaxf(ix2 - ix1, 0.f) * fmaxf(iy2 - iy1, 0.f);
                float iou = inter / (ai + aj - inter + 1e-9f);
                if (iou > MIN_IOU_F) bits |= 1ull << (j & 63);
            }
            sup[i * 8 + l] = bits;
        }
        __syncthreads();
        // single-wave sequential scan, barrier-free
        if (tid < 64) {
            int l = tid;
            u64 kw = 0;
            if (l < nw) {
                int lo = l << 6;
                int cnt = V - lo;
                if (cnt > 64) cnt = 64;
                kw = (cnt >= 64) ? ~0ull : ((1ull << cnt) - 1ull);
            }
            for (int i = 0; i < V; ++i) {
                u64 srow = sup[i * 8 + (l & 7)];
                u64 kword = shfl_u64(kw, i >> 6);
                if ((kword >> (i & 63)) & 1ull)
                    kw &= ~srow;
            }
            if (l < 8) kwout[l] = (l < nw) ? kw : 0ull;
        }
        __syncthreads();
        for (int s = tid; s < V; s += NT) {
            unsigned orig = (unsigned)(skey[s] & 0xFFFFFFFFull);
            out[6 * M_BOXES + orig] =
                (float)((kwout[s >> 6] >> (s & 63)) & 1ull);
        }
    } else {
        // slow fallback (statistically unreachable for this input): byte flags
        unsigned char* keepb = smem + 32768;  // 4KB, after key region
        for (int s = tid; s < V; s += NT) keepb[s] = 1;
        __syncthreads();
        for (int i = 0; i < V; ++i) {
            if (keepb[i]) {  // uniform
                unsigned oi = (unsigned)(skey[i] & 0xFFFFFFFFull);
                float4 bi = *reinterpret_cast<const float4*>(out + 4 * oi);
                float ai = fmaxf(bi.z - bi.x, 0.f) * fmaxf(bi.w - bi.y, 0.f);
                for (int s = i + 1 + tid; s < V; s += NT) {
                    if (keepb[s]) {
                        unsigned oj = (unsigned)(skey[s] & 0xFFFFFFFFull);
                        float4 bj = *reinterpret_cast<const float4*>(out + 4 * oj);
                        float aj = fmaxf(bj.z - bj.x, 0.f) * fmaxf(bj.w - bj.y, 0.f);
                        float ix1 = fmaxf(bi.x, bj.x);
                        float iy1 = fmaxf(bi.y, bj.y);
                        float ix2 = fminf(bi.z, bj.z);
                        float iy2 = fminf(bi.w, bj.w);
                        float inter = fmaxf(ix2 - ix1, 0.f) * fmaxf(iy2 - iy1, 0.f);
                        float iou = inter / (ai + aj - inter + 1e-9f);
                        if (iou > MIN_IOU_F) keepb[s] = 0;
                    }
                }
            }
            __syncthreads();
        }
        for (int s = tid; s < V; s += NT) {
            unsigned orig = (unsigned)(skey[s] & 0xFFFFFFFFull);
            out[6 * M_BOXES + orig] = (float)keepb[s];
        }
    }
}

// Kernel 3: scale boxes/conf by keep, emit keep floats already in place.
__global__ __launch_bounds__(256) void finalize_kernel(float* __restrict__ out)
{
    int i = blockIdx.x * blockDim.x + threadIdx.x;
    if (i >= M_BOXES) return;
    float k = out[6 * M_BOXES + i];
    float4 b = *reinterpret_cast<float4*>(out + 4 * i);
    b.x *= k; b.y *= k; b.z *= k; b.w *= k;
    *reinterpret_cast<float4*>(out + 4 * i) = b;
    out[4 * M_BOXES + i] *= k;
}

extern "C" void kernel_launch(void* const* d_in, const int* in_sizes, int n_in,
                              void* d_out, int out_size, void* d_ws, size_t ws_size,
                              hipStream_t stream) {
    const float* boxes_raw = (const float*)d_in[0];
    const float* scores    = (const float*)d_in[1];
    const int*   indices   = (const int*)d_in[2];
    const int*   p_out_h   = (const int*)d_in[3];
    const int*   p_out_w   = (const int*)d_in[4];
    float* out = (float*)d_out;

    int* vcount = (int*)d_ws;
    u64* vpack  = (u64*)((char*)d_ws + 16);

    hipMemsetAsync(d_ws, 0, 16, stream);
    gather_kernel<<<M_BOXES / 256, 256, 0, stream>>>(
        boxes_raw, scores, indices, p_out_h, p_out_w, out, vpack, vcount);
    nms_kernel<<<1, NT, 0, stream>>>(out, vpack, vcount);
    finalize_kernel<<<M_BOXES / 256, 256, 0, stream>>>(out);
}